// Round 1
// 1270.901 us; speedup vs baseline: 1.3154x; 1.3154x over previous
//
#include <hip/hip_runtime.h>
#include <math.h>

// Problem dims
#define Bd   512
#define Sd   400
#define Vd   50000
#define Ed   512
#define Hd   256
#define EMBd 128
// xh = [context(512) | embed(128) | h0(256)] stride 896
#define XHs  896
#define Gd   1024   // 4*H

// d_out float offsets: output(B*V), new_coverage(B*S), h_t(B*H), c_t(B*H), new_attn(B*S), loss(1)
#define OFF_COV  25600000
#define OFF_H    25804800
#define OFF_C    25935872
#define OFF_ATTN 26066944
#define OFF_LOSS 26271744

// workspace float offsets
#define WS_XH     0
#define WS_GATES  458752
#define WS_WSAPP  983040
#define WS_PGEN   1114112
#define WS_ENERGY 1114624
#define WS_LOSSB  1319424
#define WS_RMAX   1319936
#define WS_RSCALE 1320448

typedef __attribute__((ext_vector_type(8))) short short8;
typedef __attribute__((ext_vector_type(4))) float f32x4;

__device__ __forceinline__ float sigmoid_f(float x){ return 1.f/(1.f + __expf(-x)); }
__device__ __forceinline__ float tanh_f(float x){ return 1.f - 2.f/(__expf(2.f*x) + 1.f); }

__device__ __forceinline__ void gload_lds16(const void* g, void* l){
  __builtin_amdgcn_global_load_lds((const __attribute__((address_space(1))) void*)g,
                                   (__attribute__((address_space(3))) void*)l, 16, 0, 0);
}

// ---------------- K1: context + embed gather + h0 copy into xh ----------------
__global__ __launch_bounds__(256) void k_context(
    const float* __restrict__ attn, const float* __restrict__ enc_out,
    const float* __restrict__ h0, const int* __restrict__ dec_input,
    const float* __restrict__ emb_table, float* __restrict__ xh)
{
  int b = blockIdx.x, t = threadIdx.x;
  __shared__ float sa[Sd];
  for (int s = t; s < Sd; s += 256) sa[s] = attn[(size_t)b*Sd + s];
  __syncthreads();
  const float* ep = enc_out + (size_t)b*Sd*Ed;
  float acc0 = 0.f, acc1 = 0.f;
  #pragma unroll 4
  for (int s = 0; s < Sd; ++s){
    float a = sa[s];
    acc0 += a * ep[(size_t)s*Ed + t];
    acc1 += a * ep[(size_t)s*Ed + t + 256];
  }
  float* xrow = xh + (size_t)b*XHs;
  xrow[t]       = acc0;
  xrow[t + 256] = acc1;
  if (t < EMBd){
    int tok = dec_input[b];
    xrow[Ed + t] = emb_table[(size_t)tok*EMBd + t];
  }
  xrow[Ed + EMBd + t] = h0[(size_t)b*Hd + t];
}

// ---------------- K2: gates = xh @ [W_ih|W_hh]^T + b_ih + b_hh ----------------
// tile 32 rows(b) x 64 cols(j), K=896, BK=32
__global__ __launch_bounds__(256) void k_gates(
    const float* __restrict__ xh, const float* __restrict__ W_ih,
    const float* __restrict__ W_hh, const float* __restrict__ b_ih,
    const float* __restrict__ b_hh, float* __restrict__ gates)
{
  __shared__ float Al[32*36];
  __shared__ float Wl[64*33];
  int tid = threadIdx.x;
  int col0 = blockIdx.x * 64;
  int row0 = blockIdx.y * 32;
  int cg = tid & 15, rg = tid >> 4;         // cols cg+16j (j<4), rows rg*2+i (i<2)
  float acc[2][4] = {{0,0,0,0},{0,0,0,0}};
  int alr = tid >> 3, alk = (tid & 7) * 4;  // A loader: 32r x 32k, 1 float4
  int wlj = tid >> 2, wlk = (tid & 3) * 8;  // W loader: 64j x 32k, 8 floats
  for (int kt = 0; kt < 28; ++kt){
    int k0 = kt * 32;
    float4 a4 = *(const float4*)(xh + (size_t)(row0+alr)*XHs + k0 + alk);
    *(float4*)(Al + alr*36 + alk) = a4;
    {
      const float* src;
      if (k0 < Ed + EMBd) src = W_ih + (size_t)(col0+wlj)*(Ed+EMBd) + k0 + wlk;
      else                src = W_hh + (size_t)(col0+wlj)*Hd + (k0 - (Ed+EMBd)) + wlk;
      #pragma unroll
      for (int q = 0; q < 8; ++q) Wl[wlj*33 + wlk + q] = src[q];
    }
    __syncthreads();
    #pragma unroll 4
    for (int k = 0; k < 32; ++k){
      float a0 = Al[(rg*2+0)*36 + k];
      float a1 = Al[(rg*2+1)*36 + k];
      #pragma unroll
      for (int j = 0; j < 4; ++j){
        float w = Wl[(cg + 16*j)*33 + k];
        acc[0][j] += a0 * w;
        acc[1][j] += a1 * w;
      }
    }
    __syncthreads();
  }
  #pragma unroll
  for (int i = 0; i < 2; ++i){
    int row = row0 + rg*2 + i;
    #pragma unroll
    for (int j = 0; j < 4; ++j){
      int col = col0 + cg + 16*j;
      gates[(size_t)row*Gd + col] = acc[i][j] + b_ih[col] + b_hh[col];
    }
  }
}

// ---------------- K3: LSTM cell -> h_t, c_t (into d_out) ----------------
__global__ __launch_bounds__(256) void k_lstm(
    const float* __restrict__ gates, const float* __restrict__ c0,
    float* __restrict__ dout)
{
  int idx = blockIdx.x*256 + threadIdx.x;   // B*H
  int b = idx >> 8, h = idx & 255;
  const float* g = gates + (size_t)b*Gd;
  float xi = g[h], xf = g[Hd + h], xg = g[2*Hd + h], xo = g[3*Hd + h];
  float c  = sigmoid_f(xf)*c0[idx] + sigmoid_f(xi)*tanh_f(xg);
  float ht = sigmoid_f(xo)*tanh_f(c);
  dout[OFF_C + idx] = c;
  dout[OFF_H + idx] = ht;
}

// ---------------- K3b: awh_W -> bf16 hi/lo split (one-time, into dead gates region) ---
__global__ __launch_bounds__(256) void k_wcvt(
    const float* __restrict__ W, short* __restrict__ hi, short* __restrict__ lo)
{
  int i = blockIdx.x*256 + threadIdx.x;    // 32768 threads, 4 floats each
  float4 w = ((const float4*)W)[i];
  float xs[4] = {w.x, w.y, w.z, w.w};
  short h4[4], l4[4];
  #pragma unroll
  for (int j = 0; j < 4; ++j){
    unsigned u = __float_as_uint(xs[j]);
    h4[j] = (short)(u >> 16);
    float hf = __uint_as_float(u & 0xffff0000u);
    l4[j] = (short)(__float_as_uint(xs[j] - hf) >> 16);
  }
  ((short4*)hi)[i] = make_short4(h4[0], h4[1], h4[2], h4[3]);
  ((short4*)lo)[i] = make_short4(l4[0], l4[1], l4[2], l4[3]);
}

// ---------------- K4: ws_app = h_t @ aws_W^T + aws_b ----------------
__global__ __launch_bounds__(256) void k_wsapp(
    const float* __restrict__ ht, const float* __restrict__ aws_W,
    const float* __restrict__ aws_b, float* __restrict__ wsapp)
{
  int b = blockIdx.x, t = threadIdx.x;
  __shared__ float hrow[Hd];
  hrow[t] = ht[(size_t)b*Hd + t];
  __syncthreads();
  const float4* w4 = (const float4*)(aws_W + (size_t)t*Hd);
  float acc = 0.f;
  #pragma unroll 4
  for (int k4 = 0; k4 < Hd/4; ++k4){
    float4 w = w4[k4];
    int k = k4*4;
    acc += hrow[k]*w.x + hrow[k+1]*w.y + hrow[k+2]*w.z + hrow[k+3]*w.w;
  }
  wsapp[(size_t)b*Hd + t] = acc + aws_b[t];
}

// ---------------- K5: p_gen ----------------
__global__ __launch_bounds__(256) void k_pgen(
    const float* __restrict__ xh, const float* __restrict__ ht,
    const float* __restrict__ wh, const float* __restrict__ wsv,
    const float* __restrict__ wx, float* __restrict__ pgen)
{
  int b = blockIdx.x, t = threadIdx.x;
  __shared__ float red[256];
  const float* x = xh + (size_t)b*XHs;
  float part = x[t]*wh[t] + x[t+256]*wh[t+256];     // context . wh
  part += ht[(size_t)b*Hd + t] * wsv[t];            // h_t . ws
  if (t < EMBd) part += x[Ed + t] * wx[t];          // embed . wx
  red[t] = part; __syncthreads();
  for (int off = 128; off > 0; off >>= 1){
    if (t < off) red[t] += red[t + off];
    __syncthreads();
  }
  if (t == 0) pgen[b] = sigmoid_f(red[0]);
}

// ---------------- K6: MFMA energy GEMM (split-bf16) + tanh + av-dot ----------------
// rows = b*S+s (204800), tile BM=64 rows x BN=256 cols(H), K=512, BK=32
// 4 waves; each wave computes 64 rows x 64 cols = 4x4 frags of 16x16x32.
// A (enc_out) reg-staged fp32 -> bf16 hi/lo in-kernel; B (awh_W hi/lo, pre-converted)
// staged via global_load_lds with pre-swizzled source. LDS tiles are row-major
// [r][32] bf16 with 16B-slot swizzle s' = s ^ ((r>>1)&3)  (bank-conflict-free reads).
__global__ __launch_bounds__(256) void k_energy_mfma(
    const float* __restrict__ enc_out, const short* __restrict__ Whi,
    const short* __restrict__ Wlo, const float* __restrict__ awh_b,
    const float* __restrict__ wsapp, const float* __restrict__ coverage,
    const float* __restrict__ awc, const float* __restrict__ av,
    float* __restrict__ energy)
{
  __shared__ short Ah[64*32], Alo[64*32];      // 4 KB each
  __shared__ short Bh[256*32], Blo[256*32];    // 16 KB each
  __shared__ float s_av[256], s_bias[256], s_awc[256];
  __shared__ float red[4][64];
  int tid = threadIdx.x;
  int wid = tid >> 6, lane = tid & 63;
  int row0 = blockIdx.x * 64;

  s_av[tid] = av[tid]; s_bias[tid] = awh_b[tid]; s_awc[tid] = awc[tid];

  f32x4 acc[4][4] = {};

  // A staging: thread t -> row ar, k-slot as_ (8 floats)
  int ar = tid >> 2, as_ = tid & 3;
  int a_st = ar*32 + (as_ ^ ((ar>>1)&3))*8;          // swizzled LDS short index
  const float* ag = enc_out + (size_t)(row0 + ar)*Ed + as_*8;

  // B staging: wave wid owns chunks [wid*4 .. wid*4+3]; chunk = 16 rows x 64B (1 KB)
  // HW writes lds_base + lane*16; LDS layout short idx = r*32 + s'*8 with s'=lane&3.
  int b_r[4], b_s[4];
  #pragma unroll
  for (int c = 0; c < 4; ++c){
    int ch = wid*4 + c;
    int r  = ch*16 + (lane>>2);
    b_r[c] = r;
    b_s[c] = (lane&3) ^ ((r>>1)&3);                  // pre-swizzled global slot
  }

  // fragment read addresses (constant across K-steps)
  int n0 = wid*64;
  int a_rd[4], b_rd[4];
  #pragma unroll
  for (int m = 0; m < 4; ++m){
    int r = m*16 + (lane&15);
    a_rd[m] = r*32 + (((lane>>4) ^ ((r>>1)&3)))*8;
  }
  #pragma unroll
  for (int n = 0; n < 4; ++n){
    int c = n0 + n*16 + (lane&15);
    b_rd[n] = c*32 + (((lane>>4) ^ ((c>>1)&3)))*8;
  }

  for (int kt = 0; kt < Ed/32; ++kt){
    int k0 = kt*32;
    // B: async global->LDS (bf16 hi/lo already)
    #pragma unroll
    for (int c = 0; c < 4; ++c){
      int ch = wid*4 + c;
      const short* gh = Whi + (size_t)b_r[c]*Ed + k0 + b_s[c]*8;
      const short* gl = Wlo + (size_t)b_r[c]*Ed + k0 + b_s[c]*8;
      gload_lds16(gh, &Bh[ch*512]);
      gload_lds16(gl, &Blo[ch*512]);
    }
    // A: fp32 load -> hi/lo bf16 -> LDS
    float4 a0 = *(const float4*)(ag + k0);
    float4 a1 = *(const float4*)(ag + k0 + 4);
    float xs[8] = {a0.x,a0.y,a0.z,a0.w,a1.x,a1.y,a1.z,a1.w};
    short8 h8, l8;
    #pragma unroll
    for (int q = 0; q < 8; ++q){
      unsigned u = __float_as_uint(xs[q]);
      h8[q] = (short)(u >> 16);
      float hf = __uint_as_float(u & 0xffff0000u);
      l8[q] = (short)(__float_as_uint(xs[q] - hf) >> 16);
    }
    *(short8*)&Ah[a_st]  = h8;
    *(short8*)&Alo[a_st] = l8;
    __syncthreads();

    short8 ah[4], al[4], bh[4], bl[4];
    #pragma unroll
    for (int m = 0; m < 4; ++m){
      ah[m] = *(const short8*)&Ah[a_rd[m]];
      al[m] = *(const short8*)&Alo[a_rd[m]];
    }
    #pragma unroll
    for (int n = 0; n < 4; ++n){
      bh[n] = *(const short8*)&Bh[b_rd[n]];
      bl[n] = *(const short8*)&Blo[b_rd[n]];
    }
    #pragma unroll
    for (int m = 0; m < 4; ++m){
      #pragma unroll
      for (int n = 0; n < 4; ++n){
        acc[m][n] = __builtin_amdgcn_mfma_f32_16x16x32_bf16(ah[m], bh[n], acc[m][n], 0, 0, 0);
        acc[m][n] = __builtin_amdgcn_mfma_f32_16x16x32_bf16(ah[m], bl[n], acc[m][n], 0, 0, 0);
        acc[m][n] = __builtin_amdgcn_mfma_f32_16x16x32_bf16(al[m], bh[n], acc[m][n], 0, 0, 0);
      }
    }
    __syncthreads();
  }

  // epilogue: energy[row] = sum_h av[h]*tanh(E + awh_b[h] + wsapp[b][h] + cov*awc[h])
  // C/D frag layout: col = lane&15, row = (lane>>4)*4 + reg   [m89]
  int b0 = row0 / Sd;
  int b1 = b0 + 1; if (b1 > Bd-1) b1 = Bd-1;
  int split = (b0 + 1) * Sd;
  float avv[4], bbv[4], wcv[4], wv0[4], wv1[4];
  #pragma unroll
  for (int n = 0; n < 4; ++n){
    int h = n0 + n*16 + (lane&15);
    avv[n] = s_av[h]; bbv[n] = s_bias[h]; wcv[n] = s_awc[h];
    wv0[n] = wsapp[(size_t)b0*Hd + h];
    wv1[n] = wsapp[(size_t)b1*Hd + h];
  }
  #pragma unroll
  for (int m = 0; m < 4; ++m){
    #pragma unroll
    for (int j = 0; j < 4; ++j){
      int rt = m*16 + ((lane>>4)<<2) + j;
      int grow = row0 + rt;
      bool hib = (grow >= split);
      float cov = coverage[grow];
      float part = 0.f;
      #pragma unroll
      for (int n = 0; n < 4; ++n){
        float x = acc[m][n][j] + bbv[n] + (hib ? wv1[n] : wv0[n]) + cov*wcv[n];
        part += avv[n]*tanh_f(x);
      }
      part += __shfl_xor(part, 1, 16);
      part += __shfl_xor(part, 2, 16);
      part += __shfl_xor(part, 4, 16);
      part += __shfl_xor(part, 8, 16);
      if ((lane & 15) == 0) red[wid][rt] = part;
    }
  }
  __syncthreads();
  if (tid < 64)
    energy[row0 + tid] = red[0][tid] + red[1][tid] + red[2][tid] + red[3][tid];
}

// ---------------- K7: attn softmax + new_coverage + per-b loss ----------------
__global__ __launch_bounds__(256) void k_attn_softmax(
    const float* __restrict__ energy, const float* __restrict__ coverage,
    float* __restrict__ dout, float* __restrict__ loss_b)
{
  int b = blockIdx.x, t = threadIdx.x;
  __shared__ float red[256];
  const float* e = energy + (size_t)b*Sd;
  float e0 = e[t];
  float e1 = (t + 256 < Sd) ? e[t+256] : -1e30f;
  red[t] = fmaxf(e0, e1); __syncthreads();
  for (int off = 128; off > 0; off >>= 1){
    if (t < off) red[t] = fmaxf(red[t], red[t+off]);
    __syncthreads();
  }
  float m = red[0]; __syncthreads();
  float p0 = __expf(e0 - m);
  float p1 = (t + 256 < Sd) ? __expf(e1 - m) : 0.f;
  red[t] = p0 + p1; __syncthreads();
  for (int off = 128; off > 0; off >>= 1){
    if (t < off) red[t] += red[t+off];
    __syncthreads();
  }
  float inv = 1.f / red[0]; __syncthreads();
  float* attn_o = dout + OFF_ATTN + (size_t)b*Sd;
  float* cov_o  = dout + OFF_COV  + (size_t)b*Sd;
  float a0 = p0 * inv;
  float cv0 = coverage[(size_t)b*Sd + t];
  attn_o[t] = a0; cov_o[t] = cv0 + a0;
  float lp = fminf(a0, cv0);
  if (t + 256 < Sd){
    float a1 = p1 * inv;
    float cv1 = coverage[(size_t)b*Sd + t + 256];
    attn_o[t+256] = a1; cov_o[t+256] = cv1 + a1;
    lp += fminf(a1, cv1);
  }
  red[t] = lp; __syncthreads();
  for (int off = 128; off > 0; off >>= 1){
    if (t < off) red[t] += red[t+off];
    __syncthreads();
  }
  if (t == 0) loss_b[b] = red[0];
}

__global__ void k_loss(const float* __restrict__ loss_b, float* __restrict__ dout)
{
  __shared__ float red[256];
  int t = threadIdx.x;
  red[t] = loss_b[t] + loss_b[t + 256];
  __syncthreads();
  for (int off = 128; off > 0; off >>= 1){
    if (t < off) red[t] += red[t+off];
    __syncthreads();
  }
  if (t == 0) dout[OFF_LOSS] = red[0];
}

// ---------------- K8: logits = h_t @ v_W^T + v_b (into d_out[0:B*V]) ----------------
// tile 64 rows(b) x 256 cols(v), K=256, BK=32
__global__ __launch_bounds__(256) void k_logits(
    const float* __restrict__ ht, const float* __restrict__ v_W,
    const float* __restrict__ v_b, float* __restrict__ out)
{
  __shared__ float Al[32*68];
  __shared__ float Wl[32*258];
  int tid = threadIdx.x;
  int col0 = blockIdx.x * 256;
  int row0 = blockIdx.y * 64;
  int cg = tid & 31, rg = tid >> 5;
  float acc[8][8];
  #pragma unroll
  for (int i=0;i<8;++i){
    #pragma unroll
    for (int j=0;j<8;++j) acc[i][j]=0.f;
  }
  int alr = tid >> 2, alk = (tid & 3) * 8;
  int wlh = tid >> 3, wlk = (tid & 7) * 4;
  for (int kt = 0; kt < Hd/32; ++kt){
    int k0 = kt * 32;
    const float* ap = ht + (size_t)(row0 + alr)*Hd + k0 + alk;
    float4 x0 = *(const float4*)ap;
    float4 x1 = *(const float4*)(ap + 4);
    Al[(alk+0)*68 + alr] = x0.x; Al[(alk+1)*68 + alr] = x0.y;
    Al[(alk+2)*68 + alr] = x0.z; Al[(alk+3)*68 + alr] = x0.w;
    Al[(alk+4)*68 + alr] = x1.x; Al[(alk+5)*68 + alr] = x1.y;
    Al[(alk+6)*68 + alr] = x1.z; Al[(alk+7)*68 + alr] = x1.w;
    #pragma unroll
    for (int p = 0; p < 8; ++p){
      int h = wlh + 32*p;
      int v = col0 + h; if (v > Vd-1) v = Vd-1;
      float4 w4 = *(const float4*)(v_W + (size_t)v*Hd + k0 + wlk);
      Wl[(wlk+0)*258 + h] = w4.x; Wl[(wlk+1)*258 + h] = w4.y;
      Wl[(wlk+2)*258 + h] = w4.z; Wl[(wlk+3)*258 + h] = w4.w;
    }
    __syncthreads();
    #pragma unroll 4
    for (int k = 0; k < 32; ++k){
      float a[8], w[8];
      *(float4*)(&a[0]) = *(const float4*)(Al + k*68 + rg*8);
      *(float4*)(&a[4]) = *(const float4*)(Al + k*68 + rg*8 + 4);
      #pragma unroll
      for (int j = 0; j < 4; ++j){
        float2 w2 = *(const float2*)(Wl + k*258 + cg*2 + 64*j);
        w[2*j] = w2.x; w[2*j+1] = w2.y;
      }
      #pragma unroll
      for (int i = 0; i < 8; ++i){
        #pragma unroll
        for (int j = 0; j < 8; ++j) acc[i][j] += a[i]*w[j];
      }
    }
    __syncthreads();
  }
  #pragma unroll
  for (int i = 0; i < 8; ++i){
    int row = row0 + rg*8 + i;
    float* orow = out + (size_t)row*Vd;
    #pragma unroll
    for (int j = 0; j < 4; ++j){
      int v0 = col0 + cg*2 + 64*j;
      if (v0 < Vd){
        float2 r;
        r.x = acc[i][2*j]   + v_b[v0];
        r.y = acc[i][2*j+1] + v_b[v0+1];
        *(float2*)(orow + v0) = r;
      }
    }
  }
}

// ---------------- K9: per-row vocab max & scale ----------------
__global__ __launch_bounds__(256) void k_vocab_stats(
    const float* __restrict__ logits, const float* __restrict__ pgen,
    float* __restrict__ rmax, float* __restrict__ rscale)
{
  int b = blockIdx.x, t = threadIdx.x;
  __shared__ float red[256];
  const float4* row = (const float4*)(logits + (size_t)b*Vd);
  float m = -1e30f;
  for (int i = t; i < Vd/4; i += 256){
    float4 x = row[i];
    m = fmaxf(m, fmaxf(fmaxf(x.x, x.y), fmaxf(x.z, x.w)));
  }
  red[t] = m; __syncthreads();
  for (int off = 128; off > 0; off >>= 1){
    if (t < off) red[t] = fmaxf(red[t], red[t+off]);
    __syncthreads();
  }
  m = red[0]; __syncthreads();
  float s = 0.f;
  for (int i = t; i < Vd/4; i += 256){
    float4 x = row[i];
    s += __expf(x.x-m) + __expf(x.y-m) + __expf(x.z-m) + __expf(x.w-m);
  }
  red[t] = s; __syncthreads();
  for (int off = 128; off > 0; off >>= 1){
    if (t < off) red[t] += red[t+off];
    __syncthreads();
  }
  if (t == 0){ rmax[b] = m; rscale[b] = pgen[b] / red[0]; }
}

// ---------------- K10: normalize logits -> p_gen * p_vocab ----------------
__global__ __launch_bounds__(256) void k_vocab_norm(
    float* __restrict__ out, const float* __restrict__ rmax,
    const float* __restrict__ rscale)
{
  long long i4 = (long long)blockIdx.x*256 + threadIdx.x;  // exactly B*V/4 threads
  int b = (int)(i4 / (Vd/4));
  float m = rmax[b], sc = rscale[b];
  float4* o = (float4*)out;
  float4 x = o[i4];
  x.x = sc*__expf(x.x - m); x.y = sc*__expf(x.y - m);
  x.z = sc*__expf(x.z - m); x.w = sc*__expf(x.w - m);
  o[i4] = x;
}

// ---------------- K11: scatter-add of (1-p_gen)*new_attn with .set semantics ----------------
__global__ __launch_bounds__(256) void k_scatter(
    const int* __restrict__ enc_inputs, const float* __restrict__ pgen,
    float* __restrict__ dout)
{
  int idx = blockIdx.x*256 + threadIdx.x;    // B*S
  int b = idx / Sd, s = idx - b*Sd;
  const int* row = enc_inputs + (size_t)b*Sd;
  int v = row[s];
  // last-write-wins: only the last occurrence of v in this row writes
  for (int s2 = s+1; s2 < Sd; ++s2) if (row[s2] == v) return;
  float pg = pgen[b];
  float a = dout[OFF_ATTN + idx];
  float* p = dout + (size_t)b*Vd + v;
  *p = *p + (1.f - pg)*a;
}

extern "C" void kernel_launch(void* const* d_in, const int* in_sizes, int n_in,
                              void* d_out, int out_size, void* d_ws, size_t ws_size,
                              hipStream_t stream)
{
  const float* coverage   = (const float*)d_in[0];
  const float* enc_out    = (const float*)d_in[1];
  const float* h0         = (const float*)d_in[2];
  const float* c0         = (const float*)d_in[3];
  const float* attn       = (const float*)d_in[4];
  const int*   dec_input  = (const int*)  d_in[5];
  const int*   enc_inputs = (const int*)  d_in[6];
  const float* emb_table  = (const float*)d_in[7];
  const float* W_ih       = (const float*)d_in[8];
  const float* W_hh       = (const float*)d_in[9];
  const float* b_ih       = (const float*)d_in[10];
  const float* b_hh       = (const float*)d_in[11];
  const float* awh_W      = (const float*)d_in[12];
  const float* awh_b      = (const float*)d_in[13];
  const float* aws_W      = (const float*)d_in[14];
  const float* aws_b      = (const float*)d_in[15];
  const float* awc        = (const float*)d_in[16];
  const float* av         = (const float*)d_in[17];
  const float* wh         = (const float*)d_in[18];
  const float* wsv        = (const float*)d_in[19];
  const float* wx         = (const float*)d_in[20];
  const float* v_W        = (const float*)d_in[21];
  const float* v_b        = (const float*)d_in[22];
  float* out = (float*)d_out;
  float* ws  = (float*)d_ws;

  float* xh     = ws + WS_XH;
  float* gates  = ws + WS_GATES;
  float* wsapp  = ws + WS_WSAPP;
  float* pgen   = ws + WS_PGEN;
  float* energy = ws + WS_ENERGY;
  float* loss_b = ws + WS_LOSSB;
  float* rmax   = ws + WS_RMAX;
  float* rscale = ws + WS_RSCALE;
  float* ht = out + OFF_H;

  // bf16 hi/lo copies of awh_W live in the gates region (dead after k_lstm)
  short* Whi = (short*)gates;
  short* Wlo = Whi + 256*512;

  k_context<<<Bd, 256, 0, stream>>>(attn, enc_out, h0, dec_input, emb_table, xh);
  k_gates<<<dim3(Gd/64, Bd/32), 256, 0, stream>>>(xh, W_ih, W_hh, b_ih, b_hh, gates);
  k_lstm<<<(Bd*Hd)/256, 256, 0, stream>>>(gates, c0, out);
  k_wcvt<<<(Hd*Ed/4)/256, 256, 0, stream>>>(awh_W, Whi, Wlo);
  k_wsapp<<<Bd, 256, 0, stream>>>(ht, aws_W, aws_b, wsapp);
  k_pgen<<<Bd, 256, 0, stream>>>(xh, ht, wh, wsv, wx, pgen);
  k_energy_mfma<<<(Bd*Sd)/64, 256, 0, stream>>>(enc_out, Whi, Wlo, awh_b, wsapp, coverage, awc, av, energy);
  k_attn_softmax<<<Bd, 256, 0, stream>>>(energy, coverage, out, loss_b);
  k_loss<<<1, 256, 0, stream>>>(loss_b, out);
  k_logits<<<dim3((Vd + 255)/256, Bd/64), 256, 0, stream>>>(ht, v_W, v_b, out);
  k_vocab_stats<<<Bd, 256, 0, stream>>>(out, pgen, rmax, rscale);
  k_vocab_norm<<<(Bd*Vd/4)/256, 256, 0, stream>>>(out, rmax, rscale);
  k_scatter<<<(Bd*Sd)/256, 256, 0, stream>>>(enc_inputs, pgen, out);
}

// Round 2
// 1160.845 us; speedup vs baseline: 1.4402x; 1.0948x over previous
//
#include <hip/hip_runtime.h>
#include <math.h>

// Problem dims
#define Bd   512
#define Sd   400
#define Vd   50000
#define Ed   512
#define Hd   256
#define EMBd 128
// xh = [context(512) | embed(128) | h0(256)] stride 896
#define XHs  896
#define Gd   1024   // 4*H

// d_out float offsets: output(B*V), new_coverage(B*S), h_t(B*H), c_t(B*H), new_attn(B*S), loss(1)
#define OFF_COV  25600000
#define OFF_H    25804800
#define OFF_C    25935872
#define OFF_ATTN 26066944
#define OFF_LOSS 26271744

// workspace float offsets
#define WS_XH     0
#define WS_GATES  458752
#define WS_WSAPP  983040
#define WS_PGEN   1114112
#define WS_ENERGY 1114624
#define WS_LOSSB  1319424
#define WS_RMAX   1319936
#define WS_RSCALE 1320448
// bf16 stashes inside the dead gates region [458752 .. 983040):
//   Whi/Wlo (awh_W hi/lo)  : floats 458752 .. 589824  (262144 shorts)
//   ht_bf (h_t bf16, RTN)  : floats 589824 .. 655360  (131072 shorts)
#define WS_HTBF   589824

typedef __attribute__((ext_vector_type(8))) short short8;
typedef __attribute__((ext_vector_type(4))) float f32x4;

__device__ __forceinline__ float sigmoid_f(float x){ return 1.f/(1.f + __expf(-x)); }
__device__ __forceinline__ float tanh_f(float x){ return 1.f - 2.f/(__expf(2.f*x) + 1.f); }

__device__ __forceinline__ void gload_lds16(const void* g, void* l){
  __builtin_amdgcn_global_load_lds((const __attribute__((address_space(1))) void*)g,
                                   (__attribute__((address_space(3))) void*)l, 16, 0, 0);
}

// ---------------- K1: context + embed gather + h0 copy into xh ----------------
__global__ __launch_bounds__(256) void k_context(
    const float* __restrict__ attn, const float* __restrict__ enc_out,
    const float* __restrict__ h0, const int* __restrict__ dec_input,
    const float* __restrict__ emb_table, float* __restrict__ xh)
{
  int b = blockIdx.x, t = threadIdx.x;
  __shared__ float sa[Sd];
  for (int s = t; s < Sd; s += 256) sa[s] = attn[(size_t)b*Sd + s];
  __syncthreads();
  const float* ep = enc_out + (size_t)b*Sd*Ed;
  float acc0 = 0.f, acc1 = 0.f;
  #pragma unroll 4
  for (int s = 0; s < Sd; ++s){
    float a = sa[s];
    acc0 += a * ep[(size_t)s*Ed + t];
    acc1 += a * ep[(size_t)s*Ed + t + 256];
  }
  float* xrow = xh + (size_t)b*XHs;
  xrow[t]       = acc0;
  xrow[t + 256] = acc1;
  if (t < EMBd){
    int tok = dec_input[b];
    xrow[Ed + t] = emb_table[(size_t)tok*EMBd + t];
  }
  xrow[Ed + EMBd + t] = h0[(size_t)b*Hd + t];
}

// ---------------- K2: gates = xh @ [W_ih|W_hh]^T + b_ih + b_hh ----------------
__global__ __launch_bounds__(256) void k_gates(
    const float* __restrict__ xh, const float* __restrict__ W_ih,
    const float* __restrict__ W_hh, const float* __restrict__ b_ih,
    const float* __restrict__ b_hh, float* __restrict__ gates)
{
  __shared__ float Al[32*36];
  __shared__ float Wl[64*33];
  int tid = threadIdx.x;
  int col0 = blockIdx.x * 64;
  int row0 = blockIdx.y * 32;
  int cg = tid & 15, rg = tid >> 4;
  float acc[2][4] = {{0,0,0,0},{0,0,0,0}};
  int alr = tid >> 3, alk = (tid & 7) * 4;
  int wlj = tid >> 2, wlk = (tid & 3) * 8;
  for (int kt = 0; kt < 28; ++kt){
    int k0 = kt * 32;
    float4 a4 = *(const float4*)(xh + (size_t)(row0+alr)*XHs + k0 + alk);
    *(float4*)(Al + alr*36 + alk) = a4;
    {
      const float* src;
      if (k0 < Ed + EMBd) src = W_ih + (size_t)(col0+wlj)*(Ed+EMBd) + k0 + wlk;
      else                src = W_hh + (size_t)(col0+wlj)*Hd + (k0 - (Ed+EMBd)) + wlk;
      #pragma unroll
      for (int q = 0; q < 8; ++q) Wl[wlj*33 + wlk + q] = src[q];
    }
    __syncthreads();
    #pragma unroll 4
    for (int k = 0; k < 32; ++k){
      float a0 = Al[(rg*2+0)*36 + k];
      float a1 = Al[(rg*2+1)*36 + k];
      #pragma unroll
      for (int j = 0; j < 4; ++j){
        float w = Wl[(cg + 16*j)*33 + k];
        acc[0][j] += a0 * w;
        acc[1][j] += a1 * w;
      }
    }
    __syncthreads();
  }
  #pragma unroll
  for (int i = 0; i < 2; ++i){
    int row = row0 + rg*2 + i;
    #pragma unroll
    for (int j = 0; j < 4; ++j){
      int col = col0 + cg + 16*j;
      gates[(size_t)row*Gd + col] = acc[i][j] + b_ih[col] + b_hh[col];
    }
  }
}

// ---------------- K3: LSTM cell -> h_t, c_t (into d_out) ----------------
__global__ __launch_bounds__(256) void k_lstm(
    const float* __restrict__ gates, const float* __restrict__ c0,
    float* __restrict__ dout)
{
  int idx = blockIdx.x*256 + threadIdx.x;   // B*H
  int b = idx >> 8, h = idx & 255;
  const float* g = gates + (size_t)b*Gd;
  float xi = g[h], xf = g[Hd + h], xg = g[2*Hd + h], xo = g[3*Hd + h];
  float c  = sigmoid_f(xf)*c0[idx] + sigmoid_f(xi)*tanh_f(xg);
  float ht = sigmoid_f(xo)*tanh_f(c);
  dout[OFF_C + idx] = c;
  dout[OFF_H + idx] = ht;
}

// ---------------- K3b: awh_W -> bf16 hi/lo split + ht -> bf16 (RTN) ----------------
// blocks 0..127: awh_W (truncation split; lo captures residual)
// blocks 128..255: ht (round-to-nearest)
__global__ __launch_bounds__(256) void k_wcvt(
    const float* __restrict__ W, short* __restrict__ hi, short* __restrict__ lo,
    const float* __restrict__ ht, short* __restrict__ htb)
{
  int bx = blockIdx.x;
  if (bx < 128){
    int i = bx*256 + threadIdx.x;    // 32768 threads, 4 floats each
    float4 w = ((const float4*)W)[i];
    float xs[4] = {w.x, w.y, w.z, w.w};
    short h4[4], l4[4];
    #pragma unroll
    for (int j = 0; j < 4; ++j){
      unsigned u = __float_as_uint(xs[j]);
      h4[j] = (short)(u >> 16);
      float hf = __uint_as_float(u & 0xffff0000u);
      l4[j] = (short)(__float_as_uint(xs[j] - hf) >> 16);
    }
    ((short4*)hi)[i] = make_short4(h4[0], h4[1], h4[2], h4[3]);
    ((short4*)lo)[i] = make_short4(l4[0], l4[1], l4[2], l4[3]);
  } else {
    int i = (bx - 128)*256 + threadIdx.x;   // 32768 float4 groups over B*H=131072
    float4 w = ((const float4*)ht)[i];
    short h4[4];
    h4[0] = (short)((__float_as_uint(w.x) + 0x8000u) >> 16);
    h4[1] = (short)((__float_as_uint(w.y) + 0x8000u) >> 16);
    h4[2] = (short)((__float_as_uint(w.z) + 0x8000u) >> 16);
    h4[3] = (short)((__float_as_uint(w.w) + 0x8000u) >> 16);
    ((short4*)htb)[i] = make_short4(h4[0], h4[1], h4[2], h4[3]);
  }
}

// ---------------- K4: merged ws_app + p_gen ----------------
__global__ __launch_bounds__(256) void k_post(
    const float* __restrict__ ht, const float* __restrict__ aws_W,
    const float* __restrict__ aws_b, const float* __restrict__ xh,
    const float* __restrict__ wh, const float* __restrict__ wsv,
    const float* __restrict__ wx, float* __restrict__ wsapp,
    float* __restrict__ pgen)
{
  int b = blockIdx.x, t = threadIdx.x;
  __shared__ float hrow[Hd];
  __shared__ float red[256];
  float htv = ht[(size_t)b*Hd + t];
  hrow[t] = htv;
  __syncthreads();
  const float4* w4 = (const float4*)(aws_W + (size_t)t*Hd);
  float acc = 0.f;
  #pragma unroll 4
  for (int k4 = 0; k4 < Hd/4; ++k4){
    float4 w = w4[k4];
    int k = k4*4;
    acc += hrow[k]*w.x + hrow[k+1]*w.y + hrow[k+2]*w.z + hrow[k+3]*w.w;
  }
  wsapp[(size_t)b*Hd + t] = acc + aws_b[t];
  // p_gen
  const float* x = xh + (size_t)b*XHs;
  float part = x[t]*wh[t] + x[t+256]*wh[t+256];
  part += htv * wsv[t];
  if (t < EMBd) part += x[Ed + t] * wx[t];
  red[t] = part; __syncthreads();
  for (int off = 128; off > 0; off >>= 1){
    if (t < off) red[t] += red[t + off];
    __syncthreads();
  }
  if (t == 0) pgen[b] = sigmoid_f(red[0]);
}

// ---------------- K6: MFMA energy GEMM (split-bf16) + tanh + av-dot ----------------
// LDS slimmed to exactly 40 KB -> 4 blocks/CU.
__global__ __launch_bounds__(256) void k_energy_mfma(
    const float* __restrict__ enc_out, const short* __restrict__ Whi,
    const short* __restrict__ Wlo, const float* __restrict__ awh_b,
    const float* __restrict__ wsapp, const float* __restrict__ coverage,
    const float* __restrict__ awc, const float* __restrict__ av,
    float* __restrict__ energy)
{
  __shared__ short Ah[64*32], Alo[64*32];      // 4 KB each
  __shared__ short Bh[256*32], Blo[256*32];    // 16 KB each
  int tid = threadIdx.x;
  int wid = tid >> 6, lane = tid & 63;
  int row0 = blockIdx.x * 64;

  f32x4 acc[4][4] = {};

  // A staging: thread t -> row ar, k-slot as_ (8 floats)
  int ar = tid >> 2, as_ = tid & 3;
  int a_st = ar*32 + (as_ ^ ((ar>>1)&3))*8;          // swizzled LDS short index
  const float* ag = enc_out + (size_t)(row0 + ar)*Ed + as_*8;

  // B staging: wave wid owns chunks [wid*4 .. wid*4+3]; chunk = 16 rows x 64B (1 KB)
  int b_r[4], b_s[4];
  #pragma unroll
  for (int c = 0; c < 4; ++c){
    int ch = wid*4 + c;
    int r  = ch*16 + (lane>>2);
    b_r[c] = r;
    b_s[c] = (lane&3) ^ ((r>>1)&3);                  // pre-swizzled global slot
  }

  // fragment read addresses (constant across K-steps)
  int n0 = wid*64;
  int a_rd[4], b_rd[4];
  #pragma unroll
  for (int m = 0; m < 4; ++m){
    int r = m*16 + (lane&15);
    a_rd[m] = r*32 + (((lane>>4) ^ ((r>>1)&3)))*8;
  }
  #pragma unroll
  for (int n = 0; n < 4; ++n){
    int c = n0 + n*16 + (lane&15);
    b_rd[n] = c*32 + (((lane>>4) ^ ((c>>1)&3)))*8;
  }

  for (int kt = 0; kt < Ed/32; ++kt){
    int k0 = kt*32;
    #pragma unroll
    for (int c = 0; c < 4; ++c){
      int ch = wid*4 + c;
      const short* gh = Whi + (size_t)b_r[c]*Ed + k0 + b_s[c]*8;
      const short* gl = Wlo + (size_t)b_r[c]*Ed + k0 + b_s[c]*8;
      gload_lds16(gh, &Bh[ch*512]);
      gload_lds16(gl, &Blo[ch*512]);
    }
    float4 a0 = *(const float4*)(ag + k0);
    float4 a1 = *(const float4*)(ag + k0 + 4);
    float xs[8] = {a0.x,a0.y,a0.z,a0.w,a1.x,a1.y,a1.z,a1.w};
    short8 h8, l8;
    #pragma unroll
    for (int q = 0; q < 8; ++q){
      unsigned u = __float_as_uint(xs[q]);
      h8[q] = (short)(u >> 16);
      float hf = __uint_as_float(u & 0xffff0000u);
      l8[q] = (short)(__float_as_uint(xs[q] - hf) >> 16);
    }
    *(short8*)&Ah[a_st]  = h8;
    *(short8*)&Alo[a_st] = l8;
    __syncthreads();

    short8 ah[4], al[4], bh[4], bl[4];
    #pragma unroll
    for (int m = 0; m < 4; ++m){
      ah[m] = *(const short8*)&Ah[a_rd[m]];
      al[m] = *(const short8*)&Alo[a_rd[m]];
    }
    #pragma unroll
    for (int n = 0; n < 4; ++n){
      bh[n] = *(const short8*)&Bh[b_rd[n]];
      bl[n] = *(const short8*)&Blo[b_rd[n]];
    }
    #pragma unroll
    for (int m = 0; m < 4; ++m){
      #pragma unroll
      for (int n = 0; n < 4; ++n){
        acc[m][n] = __builtin_amdgcn_mfma_f32_16x16x32_bf16(ah[m], bh[n], acc[m][n], 0, 0, 0);
        acc[m][n] = __builtin_amdgcn_mfma_f32_16x16x32_bf16(ah[m], bl[n], acc[m][n], 0, 0, 0);
        acc[m][n] = __builtin_amdgcn_mfma_f32_16x16x32_bf16(al[m], bh[n], acc[m][n], 0, 0, 0);
      }
    }
    __syncthreads();
  }

  // epilogue: energy[row] = sum_h av[h]*tanh(E + awh_b[h] + wsapp[b][h] + cov*awc[h])
  // red aliased onto dead Bh tile (all LDS reads complete after final barrier)
  float* red = (float*)Bh;
  int b0 = row0 / Sd;
  int b1 = b0 + 1; if (b1 > Bd-1) b1 = Bd-1;
  int split = (b0 + 1) * Sd;
  float avv[4], bbv[4], wcv[4], wv0[4], wv1[4];
  #pragma unroll
  for (int n = 0; n < 4; ++n){
    int h = n0 + n*16 + (lane&15);
    avv[n] = av[h]; bbv[n] = awh_b[h]; wcv[n] = awc[h];
    wv0[n] = wsapp[(size_t)b0*Hd + h];
    wv1[n] = wsapp[(size_t)b1*Hd + h];
  }
  #pragma unroll
  for (int m = 0; m < 4; ++m){
    #pragma unroll
    for (int j = 0; j < 4; ++j){
      int rt = m*16 + ((lane>>4)<<2) + j;
      int grow = row0 + rt;
      bool hib = (grow >= split);
      float cov = coverage[grow];
      float part = 0.f;
      #pragma unroll
      for (int n = 0; n < 4; ++n){
        float x = acc[m][n][j] + bbv[n] + (hib ? wv1[n] : wv0[n]) + cov*wcv[n];
        part += avv[n]*tanh_f(x);
      }
      part += __shfl_xor(part, 1, 16);
      part += __shfl_xor(part, 2, 16);
      part += __shfl_xor(part, 4, 16);
      part += __shfl_xor(part, 8, 16);
      if ((lane & 15) == 0) red[wid*64 + rt] = part;
    }
  }
  __syncthreads();
  if (tid < 64)
    energy[row0 + tid] = red[tid] + red[64 + tid] + red[128 + tid] + red[192 + tid];
}

// ---------------- K7: attn softmax + new_coverage + per-b loss ----------------
__global__ __launch_bounds__(256) void k_attn_softmax(
    const float* __restrict__ energy, const float* __restrict__ coverage,
    float* __restrict__ dout, float* __restrict__ loss_b)
{
  int b = blockIdx.x, t = threadIdx.x;
  __shared__ float red[256];
  const float* e = energy + (size_t)b*Sd;
  float e0 = e[t];
  float e1 = (t + 256 < Sd) ? e[t+256] : -1e30f;
  red[t] = fmaxf(e0, e1); __syncthreads();
  for (int off = 128; off > 0; off >>= 1){
    if (t < off) red[t] = fmaxf(red[t], red[t+off]);
    __syncthreads();
  }
  float m = red[0]; __syncthreads();
  float p0 = __expf(e0 - m);
  float p1 = (t + 256 < Sd) ? __expf(e1 - m) : 0.f;
  red[t] = p0 + p1; __syncthreads();
  for (int off = 128; off > 0; off >>= 1){
    if (t < off) red[t] += red[t+off];
    __syncthreads();
  }
  float inv = 1.f / red[0]; __syncthreads();
  float* attn_o = dout + OFF_ATTN + (size_t)b*Sd;
  float* cov_o  = dout + OFF_COV  + (size_t)b*Sd;
  float a0 = p0 * inv;
  float cv0 = coverage[(size_t)b*Sd + t];
  attn_o[t] = a0; cov_o[t] = cv0 + a0;
  float lp = fminf(a0, cv0);
  if (t + 256 < Sd){
    float a1 = p1 * inv;
    float cv1 = coverage[(size_t)b*Sd + t + 256];
    attn_o[t+256] = a1; cov_o[t+256] = cv1 + a1;
    lp += fminf(a1, cv1);
  }
  red[t] = lp; __syncthreads();
  for (int off = 128; off > 0; off >>= 1){
    if (t < off) red[t] += red[t+off];
    __syncthreads();
  }
  if (t == 0) loss_b[b] = red[0];
}

__global__ void k_loss(const float* __restrict__ loss_b, float* __restrict__ dout)
{
  __shared__ float red[256];
  int t = threadIdx.x;
  red[t] = loss_b[t] + loss_b[t + 256];
  __syncthreads();
  for (int off = 128; off > 0; off >>= 1){
    if (t < off) red[t] += red[t+off];
    __syncthreads();
  }
  if (t == 0) dout[OFF_LOSS] = red[0];
}

// ---------------- K8: logits = h_t @ v_W^T + v_b  (bf16 MFMA) ----------------
// M=512(b) x N=50176(v, 196 col-blocks) x K=256. Tile BM=128 x BN=256 x BK=32.
// A = ht_bf (pre-converted, gload_lds); B = v_W fp32 reg-staged -> bf16 RTN -> LDS.
// 4 waves: wave w -> rows (w&1)*64, cols (w>>1)*128 (4x8 frags of 16x16x32).
__global__ __launch_bounds__(256) void k_logits_mfma(
    const short* __restrict__ ht_bf, const float* __restrict__ v_W,
    const float* __restrict__ v_b, float* __restrict__ out)
{
  __shared__ short Abf[128*32];   // 8 KB
  __shared__ short Bbf[256*32];   // 16 KB
  int tid = threadIdx.x;
  int wid = tid >> 6, lane = tid & 63;
  int col0 = blockIdx.x * 256;
  int row0 = blockIdx.y * 128;
  int wr0 = (wid & 1) * 64, wc0 = (wid >> 1) * 128;

  f32x4 acc[4][8] = {};

  // A staging chunks (2 per wave): chunk ch covers rows ch*16..ch*16+15
  int ac_r[2], ac_s[2];
  #pragma unroll
  for (int c = 0; c < 2; ++c){
    int ch = wid*2 + c;
    int r = ch*16 + (lane >> 2);
    ac_r[c] = r;
    ac_s[c] = (lane & 3) ^ ((r >> 1) & 3);
  }

  // B staging: thread t stages v-row col0+t
  int vrow = col0 + tid; if (vrow > Vd - 1) vrow = Vd - 1;
  const float* bg = v_W + (size_t)vrow * Hd;
  int bsw = (tid >> 1) & 3;

  int a_rd[4], b_rd[8];
  #pragma unroll
  for (int m = 0; m < 4; ++m){
    int r = wr0 + m*16 + (lane & 15);
    a_rd[m] = r*32 + (((lane >> 4) ^ ((r >> 1) & 3)))*8;
  }
  #pragma unroll
  for (int n = 0; n < 8; ++n){
    int c = wc0 + n*16 + (lane & 15);
    b_rd[n] = c*32 + (((lane >> 4) ^ ((c >> 1) & 3)))*8;
  }

  for (int kt = 0; kt < Hd/32; ++kt){
    int k0 = kt * 32;
    #pragma unroll
    for (int c = 0; c < 2; ++c){
      const short* src = ht_bf + (size_t)(row0 + ac_r[c])*Hd + k0 + ac_s[c]*8;
      gload_lds16(src, &Abf[(wid*2 + c)*512]);
    }
    // B: 32 floats -> bf16 RTN -> packed -> swizzled ds_write
    unsigned p[16];
    #pragma unroll
    for (int q = 0; q < 8; ++q){
      float4 f = *(const float4*)(bg + k0 + q*4);
      unsigned u0 = __float_as_uint(f.x) + 0x8000u;
      unsigned u1 = __float_as_uint(f.y) + 0x8000u;
      unsigned u2 = __float_as_uint(f.z) + 0x8000u;
      unsigned u3 = __float_as_uint(f.w) + 0x8000u;
      p[q*2]   = (u1 & 0xffff0000u) | (u0 >> 16);
      p[q*2+1] = (u3 & 0xffff0000u) | (u2 >> 16);
    }
    #pragma unroll
    for (int s = 0; s < 4; ++s){
      uint4 w4; w4.x = p[s*4]; w4.y = p[s*4+1]; w4.z = p[s*4+2]; w4.w = p[s*4+3];
      *(uint4*)&Bbf[tid*32 + (s ^ bsw)*8] = w4;
    }
    __syncthreads();
    short8 a[4];
    #pragma unroll
    for (int m = 0; m < 4; ++m) a[m] = *(const short8*)&Abf[a_rd[m]];
    #pragma unroll
    for (int n = 0; n < 8; ++n){
      short8 bfr = *(const short8*)&Bbf[b_rd[n]];
      #pragma unroll
      for (int m = 0; m < 4; ++m)
        acc[m][n] = __builtin_amdgcn_mfma_f32_16x16x32_bf16(a[m], bfr, acc[m][n], 0, 0, 0);
    }
    __syncthreads();
  }

  #pragma unroll
  for (int n = 0; n < 8; ++n){
    int col = col0 + wc0 + n*16 + (lane & 15);
    if (col < Vd){
      float bias = v_b[col];
      #pragma unroll
      for (int m = 0; m < 4; ++m){
        int rbase = row0 + wr0 + m*16 + ((lane >> 4) << 2);
        #pragma unroll
        for (int j = 0; j < 4; ++j)
          out[(size_t)(rbase + j)*Vd + col] = acc[m][n][j] + bias;
      }
    }
  }
}

// ---------------- K9: per-row vocab max & scale ----------------
__global__ __launch_bounds__(256) void k_vocab_stats(
    const float* __restrict__ logits, const float* __restrict__ pgen,
    float* __restrict__ rmax, float* __restrict__ rscale)
{
  int b = blockIdx.x, t = threadIdx.x;
  __shared__ float red[256];
  const float4* row = (const float4*)(logits + (size_t)b*Vd);
  float m = -1e30f;
  for (int i = t; i < Vd/4; i += 256){
    float4 x = row[i];
    m = fmaxf(m, fmaxf(fmaxf(x.x, x.y), fmaxf(x.z, x.w)));
  }
  red[t] = m; __syncthreads();
  for (int off = 128; off > 0; off >>= 1){
    if (t < off) red[t] = fmaxf(red[t], red[t+off]);
    __syncthreads();
  }
  m = red[0]; __syncthreads();
  float s = 0.f;
  for (int i = t; i < Vd/4; i += 256){
    float4 x = row[i];
    s += __expf(x.x-m) + __expf(x.y-m) + __expf(x.z-m) + __expf(x.w-m);
  }
  red[t] = s; __syncthreads();
  for (int off = 128; off > 0; off >>= 1){
    if (t < off) red[t] += red[t+off];
    __syncthreads();
  }
  if (t == 0){ rmax[b] = m; rscale[b] = pgen[b] / red[0]; }
}

// ---------------- K10: normalize logits -> p_gen * p_vocab ----------------
__global__ __launch_bounds__(256) void k_vocab_norm(
    float* __restrict__ out, const float* __restrict__ rmax,
    const float* __restrict__ rscale)
{
  long long i4 = (long long)blockIdx.x*256 + threadIdx.x;  // exactly B*V/4 threads
  int b = (int)(i4 / (Vd/4));
  float m = rmax[b], sc = rscale[b];
  float4* o = (float4*)out;
  float4 x = o[i4];
  x.x = sc*__expf(x.x - m); x.y = sc*__expf(x.y - m);
  x.z = sc*__expf(x.z - m); x.w = sc*__expf(x.w - m);
  o[i4] = x;
}

// ---------------- K11: scatter-add of (1-p_gen)*new_attn with .set semantics ----------------
__global__ __launch_bounds__(256) void k_scatter(
    const int* __restrict__ enc_inputs, const float* __restrict__ pgen,
    float* __restrict__ dout)
{
  int idx = blockIdx.x*256 + threadIdx.x;    // B*S
  int b = idx / Sd, s = idx - b*Sd;
  const int* row = enc_inputs + (size_t)b*Sd;
  int v = row[s];
  for (int s2 = s+1; s2 < Sd; ++s2) if (row[s2] == v) return;
  float pg = pgen[b];
  float a = dout[OFF_ATTN + idx];
  float* p = dout + (size_t)b*Vd + v;
  *p = *p + (1.f - pg)*a;
}

extern "C" void kernel_launch(void* const* d_in, const int* in_sizes, int n_in,
                              void* d_out, int out_size, void* d_ws, size_t ws_size,
                              hipStream_t stream)
{
  const float* coverage   = (const float*)d_in[0];
  const float* enc_out    = (const float*)d_in[1];
  const float* h0         = (const float*)d_in[2];
  const float* c0         = (const float*)d_in[3];
  const float* attn       = (const float*)d_in[4];
  const int*   dec_input  = (const int*)  d_in[5];
  const int*   enc_inputs = (const int*)  d_in[6];
  const float* emb_table  = (const float*)d_in[7];
  const float* W_ih       = (const float*)d_in[8];
  const float* W_hh       = (const float*)d_in[9];
  const float* b_ih       = (const float*)d_in[10];
  const float* b_hh       = (const float*)d_in[11];
  const float* awh_W      = (const float*)d_in[12];
  const float* awh_b      = (const float*)d_in[13];
  const float* aws_W      = (const float*)d_in[14];
  const float* aws_b      = (const float*)d_in[15];
  const float* awc        = (const float*)d_in[16];
  const float* av         = (const float*)d_in[17];
  const float* wh         = (const float*)d_in[18];
  const float* wsv        = (const float*)d_in[19];
  const float* wx         = (const float*)d_in[20];
  const float* v_W        = (const float*)d_in[21];
  const float* v_b        = (const float*)d_in[22];
  float* out = (float*)d_out;
  float* ws  = (float*)d_ws;

  float* xh     = ws + WS_XH;
  float* gates  = ws + WS_GATES;
  float* wsapp  = ws + WS_WSAPP;
  float* pgen   = ws + WS_PGEN;
  float* energy = ws + WS_ENERGY;
  float* loss_b = ws + WS_LOSSB;
  float* rmax   = ws + WS_RMAX;
  float* rscale = ws + WS_RSCALE;
  float* ht = out + OFF_H;

  // bf16 stashes in the gates region (dead after k_lstm)
  short* Whi   = (short*)gates;
  short* Wlo   = Whi + 256*512;
  short* ht_bf = (short*)(ws + WS_HTBF);

  k_context<<<Bd, 256, 0, stream>>>(attn, enc_out, h0, dec_input, emb_table, xh);
  k_gates<<<dim3(Gd/64, Bd/32), 256, 0, stream>>>(xh, W_ih, W_hh, b_ih, b_hh, gates);
  k_lstm<<<(Bd*Hd)/256, 256, 0, stream>>>(gates, c0, out);
  k_wcvt<<<256, 256, 0, stream>>>(awh_W, Whi, Wlo, ht, ht_bf);
  k_post<<<Bd, 256, 0, stream>>>(ht, aws_W, aws_b, xh, wh, wsv, wx, wsapp, pgen);
  k_energy_mfma<<<(Bd*Sd)/64, 256, 0, stream>>>(enc_out, Whi, Wlo, awh_b, wsapp, coverage, awc, av, energy);
  k_attn_softmax<<<Bd, 256, 0, stream>>>(energy, coverage, out, loss_b);
  k_loss<<<1, 256, 0, stream>>>(loss_b, out);
  k_logits_mfma<<<dim3((Vd + 255)/256, Bd/128), 256, 0, stream>>>(ht_bf, v_W, v_b, out);
  k_vocab_stats<<<Bd, 256, 0, stream>>>(out, pgen, rmax, rscale);
  k_vocab_norm<<<(Bd*Vd/4)/256, 256, 0, stream>>>(out, rmax, rscale);
  k_scatter<<<(Bd*Sd)/256, 256, 0, stream>>>(enc_inputs, pgen, out);
}